// Round 1
// baseline (350.812 us; speedup 1.0000x reference)
//
#include <hip/hip_runtime.h>
#include <math.h>

#define EPSF 1e-20f
#define Bv 4
#define Cv 32
#define Ov 32
#define Hv 256
#define Wv 256
#define HOv 128
#define WOv 128

// tile config: 4 rows x 32 cols of output per 128-thread block
#define TH 4
#define TW 32
#define IH 9     // 2*TH+1 input rows
#define IW 65    // 2*TW+1 input cols
#define IWP 66   // padded stride
#define NTILE (IH * IW)  // 585

__device__ __forceinline__ float softplus_f(float x) {
    // stable: max(x,0) + log1p(exp(-|x|))
    return fmaxf(x, 0.0f) + log1pf(__expf(-fabsf(x)));
}

__device__ __forceinline__ float frcp(float x) {
    return __builtin_amdgcn_rcpf(x);
}

// ws layout (floats): [0..31]=wp, [32..319]=sw (c*9+k), [320..1343]=cw (o*32+c),
// [1344]=1/(sum_sw+EPS), [1345]=1/(sum_cw+EPS)
__global__ void prep_kernel(const float* __restrict__ wp_raw,
                            const float* __restrict__ sw_raw,
                            const float* __restrict__ cw_raw,
                            float* __restrict__ ws) {
    __shared__ float red_sw[256];
    __shared__ float red_cw[256];
    const int t = threadIdx.x;
    float acc_sw = 0.f, acc_cw = 0.f;
    if (t < 32) ws[t] = softplus_f(wp_raw[t]);
    for (int i = t; i < 288; i += 256) {
        float v = softplus_f(sw_raw[i]);
        ws[32 + i] = v;
        acc_sw += v;
    }
    for (int i = t; i < 1024; i += 256) {
        float v = softplus_f(cw_raw[i]);
        ws[320 + i] = v;
        acc_cw += v;
    }
    red_sw[t] = acc_sw;
    red_cw[t] = acc_cw;
    __syncthreads();
    for (int st = 128; st > 0; st >>= 1) {
        if (t < st) { red_sw[t] += red_sw[t + st]; red_cw[t] += red_cw[t + st]; }
        __syncthreads();
    }
    if (t == 0) {
        ws[1344] = 1.0f / (red_sw[0] + EPSF);
        ws[1345] = 1.0f / (red_cw[0] + EPSF);
    }
}

__global__ __launch_bounds__(128)
void main_kernel(const float* __restrict__ d,  const float* __restrict__ cd,
                 const float* __restrict__ s,  const float* __restrict__ gx,
                 const float* __restrict__ cgx, const float* __restrict__ sprod,
                 const float* __restrict__ bias, const float* __restrict__ ws,
                 float* __restrict__ out) {
    __shared__ float lgx[IH][IWP];
    __shared__ float lcgx[IH][IWP];

    const int t    = threadIdx.x;
    const int wo_l = t & 31;
    const int ho_l = t >> 5;                 // 0..3
    const int wo0  = blockIdx.x * TW;        // 0,32,64,96
    const int ho0  = blockIdx.y * TH;        // 0..124
    const int b    = blockIdx.z;
    const int ho   = ho0 + ho_l;
    const int wo   = wo0 + wo_l;

    const float* sw_t = ws + 32;
    const float* cw_t = ws + 320;
    const float inv_sumsw = ws[1344];
    const float inv_sumcw = ws[1345];

    float nom2[Ov], den2[Ov];
#pragma unroll
    for (int o = 0; o < Ov; ++o) { nom2[o] = 0.f; den2[o] = 0.f; }

    const int h_base = 2 * ho0 - 1;
    const int w_base = 2 * wo0 - 1;

    for (int c = 0; c < Cv; ++c) {
        const float wpc = ws[c];                       // uniform scalar load
        const float inv_wp1 = frcp(wpc + 1.0f);
        const int ibase = (b * Cv + c) * (Hv * Wv);

        // ---- stage A: pointwise update, staged into LDS tile ----
        for (int idx = t; idx < NTILE; idx += 128) {
            const int r  = idx / IW;
            const int cc = idx - r * IW;
            const int h  = h_base + r;
            const int w  = w_base + cc;
            float gxn = 0.f, cgxn = 0.f;
            if ((unsigned)h < (unsigned)Hv && (unsigned)w < (unsigned)Wv) {
                const int p = ibase + h * Wv + w;
                const float dv   = d[p];
                const float cdv  = cd[p];
                const float sv   = s[p];
                const float gxv  = gx[p];
                const float cgxv = cgx[p];
                // pad_r zeros the LAST column; pad_l zeros the FIRST column
                const bool mL = (w != Wv - 1);
                const bool mR = (w != 0);
                const float dL  = mL ? dv  : 0.f;
                const float cdL = mL ? cdv : 0.f;
                const float sL  = mL ? sv  : 0.f;
                const float dR  = mR ? dv  : 0.f;
                const float cdR = mR ? cdv : 0.f;
                const float sR  = mR ? sv  : 0.f;
                const float cgx_ds = sv * sL * sR * cdL * cdR;
                const float height = (cdL * dL + cdR * dR) * frcp(cdL + cdR + EPSF);
                const float gx_ds  = (dR - dL) * 0.5f * frcp(height + EPSF);
                const float a = wpc * cgxv;
                gxn  = (a * gxv + cgx_ds * gx_ds) * frcp(a + cgx_ds + EPSF);
                cgxn = (a + cgx_ds) * inv_wp1;
            }
            lgx[r][cc]  = gxn;
            lcgx[r][cc] = cgxn;
        }
        __syncthreads();

        // ---- spatial stage: 3x3 stride-2 gather + per-channel 9-tap reduce ----
        const int spb = ((b * Cv + c) * 9 * HOv + ho) * WOv + wo;
        float nom = 0.f, den = 0.f;
#pragma unroll
        for (int k = 0; k < 9; ++k) {
            const int ki = k / 3;
            const int kj = k - ki * 3;
            const float gxr  = lgx[2 * ho_l + ki][2 * wo_l + kj];
            const float cgxr = lcgx[2 * ho_l + ki][2 * wo_l + kj];
            const float spv  = sprod[spb + k * (HOv * WOv)];
            const float cp   = cgxr * spv * sw_t[c * 9 + k];   // sw: uniform scalar
            den += cp;
            nom = fmaf(cp, gxr, nom);
        }
        const float gx_sp  = nom * frcp(den + EPSF);
        const float cgx_sp = den * inv_sumsw;
        const float t1 = cgx_sp * gx_sp;

        // ---- channel stage accumulate (cw uniform -> SGPR operands) ----
#pragma unroll
        for (int o = 0; o < Ov; ++o) {
            const float w_ = cw_t[o * Cv + c];
            nom2[o] = fmaf(t1, w_, nom2[o]);
            den2[o] = fmaf(cgx_sp, w_, den2[o]);
        }
        __syncthreads();   // protect LDS before next channel's staging
    }

    // ---- epilogue: divide, bias, devalue, write both outputs ----
    const int half = Bv * Ov * HOv * WOv;  // 2,097,152
#pragma unroll
    for (int o = 0; o < Ov; ++o) {
        const int p = ((b * Ov + o) * HOv + ho) * WOv + wo;
        const float dn = den2[o];
        const float g  = nom2[o] * frcp(dn + EPSF) + bias[o];
        out[p]        = g * 2.0f;                     // gx_out * STRIDE
        out[half + p] = dn * inv_sumcw * 0.25f;       // cgx_out / STRIDE^2
    }
}

extern "C" void kernel_launch(void* const* d_in, const int* in_sizes, int n_in,
                              void* d_out, int out_size, void* d_ws, size_t ws_size,
                              hipStream_t stream) {
    const float* d_ptr    = (const float*)d_in[0];
    const float* cd_ptr   = (const float*)d_in[1];
    const float* s_ptr    = (const float*)d_in[2];
    // d_in[3] = cs : unused by the reference
    const float* gx_ptr   = (const float*)d_in[4];
    const float* cgx_ptr  = (const float*)d_in[5];
    const float* sp_ptr   = (const float*)d_in[6];
    const float* wp_ptr   = (const float*)d_in[7];
    const float* sw_ptr   = (const float*)d_in[8];
    const float* cw_ptr   = (const float*)d_in[9];
    const float* bias_ptr = (const float*)d_in[10];
    float* out = (float*)d_out;
    float* ws  = (float*)d_ws;

    prep_kernel<<<1, 256, 0, stream>>>(wp_ptr, sw_ptr, cw_ptr, ws);

    dim3 grid(WOv / TW, HOv / TH, Bv);   // 4 x 32 x 4 = 512 blocks
    main_kernel<<<grid, 128, 0, stream>>>(d_ptr, cd_ptr, s_ptr, gx_ptr, cgx_ptr,
                                          sp_ptr, bias_ptr, ws, out);
}

// Round 2
// 283.500 us; speedup vs baseline: 1.2374x; 1.2374x over previous
//
#include <hip/hip_runtime.h>
#include <math.h>

#define EPSF 1e-20f
#define Bv 4
#define Cv 32
#define Ov 32
#define Hv 256
#define Wv 256
#define HOv 128
#define WOv 128
#define NPIX (HOv * WOv)          // 16384
#define HALF_OUT (Bv * Ov * NPIX) // 2,097,152

__device__ __forceinline__ float softplus_f(float x) {
    return fmaxf(x, 0.0f) + log1pf(__expf(-fabsf(x)));
}
__device__ __forceinline__ float frcp(float x) {
    return __builtin_amdgcn_rcpf(x);
}

// ws layout (floats):
//  [0..31]    wp (softplus)
//  [32..319]  sw (c*9+k)
//  [320..1343] cw (o*32+c)
//  [1344] 1/(sum_sw+EPS)   [1345] 1/(sum_cw+EPS)
//  [2048 ...] float2 buf[(b*32+c)*16384 + pix] = {cgx_sp*gx_sp, cgx_sp}  (16.8 MB)
#define WS_BUF_OFF 2048
#define WS_NEEDED (WS_BUF_OFF * 4 + (size_t)Bv * Cv * NPIX * 8)

__global__ void prep_kernel(const float* __restrict__ wp_raw,
                            const float* __restrict__ sw_raw,
                            const float* __restrict__ cw_raw,
                            float* __restrict__ ws) {
    __shared__ float red_sw[256];
    __shared__ float red_cw[256];
    const int t = threadIdx.x;
    float acc_sw = 0.f, acc_cw = 0.f;
    if (t < 32) ws[t] = softplus_f(wp_raw[t]);
    for (int i = t; i < 288; i += 256) {
        float v = softplus_f(sw_raw[i]);
        ws[32 + i] = v;
        acc_sw += v;
    }
    for (int i = t; i < 1024; i += 256) {
        float v = softplus_f(cw_raw[i]);
        ws[320 + i] = v;
        acc_cw += v;
    }
    red_sw[t] = acc_sw;
    red_cw[t] = acc_cw;
    __syncthreads();
    for (int st = 128; st > 0; st >>= 1) {
        if (t < st) { red_sw[t] += red_sw[t + st]; red_cw[t] += red_cw[t + st]; }
        __syncthreads();
    }
    if (t == 0) {
        ws[1344] = 1.0f / (red_sw[0] + EPSF);
        ws[1345] = 1.0f / (red_cw[0] + EPSF);
    }
}

// ================= K1: stage A (pointwise) + spatial 9-tap stage ==========
// tile: 8 output rows x 32 output cols per 256-thread block
// input tile: 17 rows x 65 cols, stored even/odd column-deinterleaved in LDS
#define TH1 8
#define TW1 32
#define IH1 17
#define IW1 65
#define NT1 (IH1 * IW1)   // 1105
#define ESTRIDE 34        // even/odd sub-array row stride
#define HALFT (IH1 * ESTRIDE)  // 578: offset of odd-column sub-array

__global__ __launch_bounds__(256)
void k1_spatial(const float* __restrict__ d,  const float* __restrict__ cd,
                const float* __restrict__ s,  const float* __restrict__ gx,
                const float* __restrict__ cgx, const float* __restrict__ sprod,
                const float* __restrict__ ws, float2* __restrict__ buf) {
    __shared__ float lgx[2 * HALFT];
    __shared__ float lcg[2 * HALFT];

    const int t    = threadIdx.x;
    const int wo_l = t & 31;
    const int ho_l = t >> 5;              // 0..7
    const int wo0  = blockIdx.x * TW1;
    const int ho0  = blockIdx.y * TH1;
    const int z    = blockIdx.z;          // b*32 + c
    const int c    = z & 31;
    const int b    = z >> 5;
    const int ho   = ho0 + ho_l;
    const int wo   = wo0 + wo_l;

    const float wpc = ws[c];              // uniform (scalar)
    const float inv_wp1 = frcp(wpc + 1.0f);
    const float inv_sumsw = ws[1344];
    const float* sw_c = ws + 32 + c * 9;

    const int ibase  = z * (Hv * Wv);
    const int h_base = 2 * ho0 - 1;
    const int w_base = 2 * wo0 - 1;

    // ---- stage A into LDS (even/odd deinterleaved) ----
    for (int idx = t; idx < NT1; idx += 256) {
        const int r  = idx / IW1;
        const int cc = idx - r * IW1;
        const int h  = h_base + r;
        const int w  = w_base + cc;
        float gxn = 0.f, cgn = 0.f;
        if ((unsigned)h < (unsigned)Hv && (unsigned)w < (unsigned)Wv) {
            const int p = ibase + h * Wv + w;
            const float dv   = d[p];
            const float cdv  = cd[p];
            const float sv   = s[p];
            const float gxv  = gx[p];
            const float cgv  = cgx[p];
            const bool mL = (w != Wv - 1);   // pad_r zeros last col
            const bool mR = (w != 0);        // pad_l zeros first col
            const float dL  = mL ? dv  : 0.f;
            const float cdL = mL ? cdv : 0.f;
            const float sL  = mL ? sv  : 0.f;
            const float dR  = mR ? dv  : 0.f;
            const float cdR = mR ? cdv : 0.f;
            const float sR  = mR ? sv  : 0.f;
            const float cgx_ds = sv * sL * sR * cdL * cdR;
            const float height = (cdL * dL + cdR * dR) * frcp(cdL + cdR + EPSF);
            const float gx_ds  = (dR - dL) * 0.5f * frcp(height + EPSF);
            const float a = wpc * cgv;
            gxn = (a * gxv + cgx_ds * gx_ds) * frcp(a + cgx_ds + EPSF);
            cgn = (a + cgx_ds) * inv_wp1;
        }
        const int laddr = (cc & 1) * HALFT + r * ESTRIDE + (cc >> 1);
        lgx[laddr] = gxn;
        lcg[laddr] = cgn;
    }
    __syncthreads();

    // ---- spatial stage ----
    const int spb = (z * 9 * HOv + ho) * WOv + wo;
    float nom = 0.f, den = 0.f;
#pragma unroll
    for (int k = 0; k < 9; ++k) {
        const int ki = k / 3;
        const int kj = k - ki * 3;
        const int ir = 2 * ho_l + ki;
        // col = 2*wo_l + kj  ->  even sub-array idx wo_l + (kj>>1); odd: wo_l
        const int laddr = (kj == 1) ? (HALFT + ir * ESTRIDE + wo_l)
                                    : (ir * ESTRIDE + wo_l + (kj >> 1));
        const float gxr = lgx[laddr];
        const float cgr = lcg[laddr];
        const float spv = sprod[spb + k * NPIX];
        const float cp  = cgr * spv * sw_c[k];
        den += cp;
        nom = fmaf(cp, gxr, nom);
    }
    const float gx_sp  = nom * frcp(den + EPSF);
    const float cgx_sp = den * inv_sumsw;
    buf[z * NPIX + ho * WOv + wo] = make_float2(cgx_sp * gx_sp, cgx_sp);
}

// ================= K2: 32->32 channel mix (o split in 2 groups) ===========
__global__ __launch_bounds__(256)
void k2_channel(const float2* __restrict__ buf, const float* __restrict__ ws,
                const float* __restrict__ bias, float* __restrict__ out) {
    const int pg  = blockIdx.x * 256 + threadIdx.x;  // 0..65535
    const int b   = pg >> 14;
    const int pp  = pg & (NPIX - 1);
    const int grp = blockIdx.y;                      // 0..1
    const float* cw_t = ws + 320;
    const float inv_sumcw = ws[1345];

    float nom2[16], den2[16];
#pragma unroll
    for (int i = 0; i < 16; ++i) { nom2[i] = 0.f; den2[i] = 0.f; }

    const int cbase = b * Cv * NPIX + pp;
#pragma unroll 4
    for (int cc = 0; cc < Cv; ++cc) {
        const float2 v = buf[cbase + cc * NPIX];
#pragma unroll
        for (int oi = 0; oi < 16; ++oi) {
            const float w_ = cw_t[(grp * 16 + oi) * Cv + cc];  // uniform
            nom2[oi] = fmaf(v.x, w_, nom2[oi]);
            den2[oi] = fmaf(v.y, w_, den2[oi]);
        }
    }
#pragma unroll
    for (int oi = 0; oi < 16; ++oi) {
        const int o = grp * 16 + oi;
        const int p = (b * Ov + o) * NPIX + pp;
        const float dn = den2[oi];
        const float g  = nom2[oi] * frcp(dn + EPSF) + bias[o];
        out[p]            = g * 2.0f;
        out[HALF_OUT + p] = dn * inv_sumcw * 0.25f;
    }
}

// ================= fallback: fully fused (round-1) kernel =================
#define TH 4
#define TW 32
#define IH 9
#define IW 65
#define IWP 66
#define NTILE (IH * IW)

__global__ __launch_bounds__(128)
void main_kernel(const float* __restrict__ d,  const float* __restrict__ cd,
                 const float* __restrict__ s,  const float* __restrict__ gx,
                 const float* __restrict__ cgx, const float* __restrict__ sprod,
                 const float* __restrict__ bias, const float* __restrict__ ws,
                 float* __restrict__ out) {
    __shared__ float lgx[IH][IWP];
    __shared__ float lcgx[IH][IWP];
    const int t    = threadIdx.x;
    const int wo_l = t & 31;
    const int ho_l = t >> 5;
    const int wo0  = blockIdx.x * TW;
    const int ho0  = blockIdx.y * TH;
    const int b    = blockIdx.z;
    const int ho   = ho0 + ho_l;
    const int wo   = wo0 + wo_l;
    const float* sw_t = ws + 32;
    const float* cw_t = ws + 320;
    const float inv_sumsw = ws[1344];
    const float inv_sumcw = ws[1345];
    float nom2[Ov], den2[Ov];
#pragma unroll
    for (int o = 0; o < Ov; ++o) { nom2[o] = 0.f; den2[o] = 0.f; }
    const int h_base = 2 * ho0 - 1;
    const int w_base = 2 * wo0 - 1;
    for (int c = 0; c < Cv; ++c) {
        const float wpc = ws[c];
        const float inv_wp1 = frcp(wpc + 1.0f);
        const int ibase = (b * Cv + c) * (Hv * Wv);
        for (int idx = t; idx < NTILE; idx += 128) {
            const int r  = idx / IW;
            const int cc = idx - r * IW;
            const int h  = h_base + r;
            const int w  = w_base + cc;
            float gxn = 0.f, cgxn = 0.f;
            if ((unsigned)h < (unsigned)Hv && (unsigned)w < (unsigned)Wv) {
                const int p = ibase + h * Wv + w;
                const float dv = d[p], cdv = cd[p], sv = s[p];
                const float gxv = gx[p], cgxv = cgx[p];
                const bool mL = (w != Wv - 1);
                const bool mR = (w != 0);
                const float dL = mL ? dv : 0.f, cdL = mL ? cdv : 0.f, sL = mL ? sv : 0.f;
                const float dR = mR ? dv : 0.f, cdR = mR ? cdv : 0.f, sR = mR ? sv : 0.f;
                const float cgx_ds = sv * sL * sR * cdL * cdR;
                const float height = (cdL * dL + cdR * dR) * frcp(cdL + cdR + EPSF);
                const float gx_ds  = (dR - dL) * 0.5f * frcp(height + EPSF);
                const float a = wpc * cgxv;
                gxn  = (a * gxv + cgx_ds * gx_ds) * frcp(a + cgx_ds + EPSF);
                cgxn = (a + cgx_ds) * inv_wp1;
            }
            lgx[r][cc]  = gxn;
            lcgx[r][cc] = cgxn;
        }
        __syncthreads();
        const int spb = ((b * Cv + c) * 9 * HOv + ho) * WOv + wo;
        float nom = 0.f, den = 0.f;
#pragma unroll
        for (int k = 0; k < 9; ++k) {
            const int ki = k / 3;
            const int kj = k - ki * 3;
            const float gxr  = lgx[2 * ho_l + ki][2 * wo_l + kj];
            const float cgxr = lcgx[2 * ho_l + ki][2 * wo_l + kj];
            const float spv  = sprod[spb + k * NPIX];
            const float cp   = cgxr * spv * sw_t[c * 9 + k];
            den += cp;
            nom = fmaf(cp, gxr, nom);
        }
        const float gx_sp  = nom * frcp(den + EPSF);
        const float cgx_sp = den * inv_sumsw;
        const float t1 = cgx_sp * gx_sp;
#pragma unroll
        for (int o = 0; o < Ov; ++o) {
            const float w_ = cw_t[o * Cv + c];
            nom2[o] = fmaf(t1, w_, nom2[o]);
            den2[o] = fmaf(cgx_sp, w_, den2[o]);
        }
        __syncthreads();
    }
#pragma unroll
    for (int o = 0; o < Ov; ++o) {
        const int p = ((b * Ov + o) * HOv + ho) * WOv + wo;
        const float dn = den2[o];
        const float g  = nom2[o] * frcp(dn + EPSF) + bias[o];
        out[p]            = g * 2.0f;
        out[HALF_OUT + p] = dn * inv_sumcw * 0.25f;
    }
}

extern "C" void kernel_launch(void* const* d_in, const int* in_sizes, int n_in,
                              void* d_out, int out_size, void* d_ws, size_t ws_size,
                              hipStream_t stream) {
    const float* d_ptr    = (const float*)d_in[0];
    const float* cd_ptr   = (const float*)d_in[1];
    const float* s_ptr    = (const float*)d_in[2];
    // d_in[3] = cs : unused by the reference
    const float* gx_ptr   = (const float*)d_in[4];
    const float* cgx_ptr  = (const float*)d_in[5];
    const float* sp_ptr   = (const float*)d_in[6];
    const float* wp_ptr   = (const float*)d_in[7];
    const float* sw_ptr   = (const float*)d_in[8];
    const float* cw_ptr   = (const float*)d_in[9];
    const float* bias_ptr = (const float*)d_in[10];
    float* out = (float*)d_out;
    float* ws  = (float*)d_ws;

    prep_kernel<<<1, 256, 0, stream>>>(wp_ptr, sw_ptr, cw_ptr, ws);

    if (ws_size >= WS_NEEDED) {
        float2* buf = (float2*)(ws + WS_BUF_OFF);
        dim3 g1(WOv / TW1, HOv / TH1, Bv * Cv);   // 4 x 16 x 128 = 8192 blocks
        k1_spatial<<<g1, 256, 0, stream>>>(d_ptr, cd_ptr, s_ptr, gx_ptr, cgx_ptr,
                                           sp_ptr, ws, buf);
        dim3 g2((Bv * NPIX) / 256, 2, 1);         // 256 x 2 blocks
        k2_channel<<<g2, 256, 0, stream>>>(buf, ws, bias_ptr, out);
    } else {
        dim3 grid(WOv / TW, HOv / TH, Bv);
        main_kernel<<<grid, 128, 0, stream>>>(d_ptr, cd_ptr, s_ptr, gx_ptr, cgx_ptr,
                                              sp_ptr, bias_ptr, ws, out);
    }
}